// Round 3
// baseline (222.752 us; speedup 1.0000x reference)
//
#include <hip/hip_runtime.h>
#include <hip/hip_bf16.h>
#include <stdint.h>

// MoE grouped linear: y[t] = relu(x[t] @ W[idxs[t]] + b[idxs[t]])
// T=16384, D_IN=D_OUT=1024, E=8.
// R9: gemm K-loop restructured from naive {bar; stage; bar+vmcnt0; compute}
// (m233: ~72% of critical path = exposed stage latency) to double-buffered
// prefetch with ONE barrier per K-step:
//   prologue: STAGE(buf0,k=0); vmcnt(0); s_barrier
//   iter t:   STAGE(buf[cur^1], k=(t+1)*64); compute(buf[cur]);
//             asm{vmcnt(0); s_barrier}; cur^=1
// Stage latency hides under compute(t). Buffer-overwrite safety: STAGE(t+1)
// writes the buffer computed at t-1; every wave passed the end-of-(t-1)
// barrier only after consuming its reads -> no race. waitcnt+s_barrier fused
// in one asm volatile w/ "memory" clobber so ds_reads can't cross it.
// LDS 33->65.5 KB (2 blocks/CU). Front unchanged from R8.

#define T_TOK 16384
#define DIN   1024
#define DOUT  1024
#define NE    8
#define BM    128
#define BN    128
#define BK    64
#define TPX   17                  // A-tiles per XCD slot (8*17 = 136)
#define MAX_TILES 136
#define MP_MAX (T_TOK + NE * BM)  // 17408 padded rows max

typedef __attribute__((ext_vector_type(8))) short short8;
typedef __attribute__((ext_vector_type(4))) short short4v;
typedef __attribute__((ext_vector_type(4))) float floatx4;
typedef __attribute__((ext_vector_type(4))) int int4v;

__device__ __forceinline__ short f2b(float f) {
  return __builtin_bit_cast(short, __float2bfloat16(f));
}
__device__ __forceinline__ float b2f(unsigned short u) {
  unsigned v = ((unsigned)u) << 16;
  return __builtin_bit_cast(float, v);
}
__device__ __forceinline__ void glds16(const void* g, void* l) {
  __builtin_amdgcn_global_load_lds(
      (__attribute__((address_space(1))) void*)g,
      (__attribute__((address_space(3))) void*)l, 16, 0, 0);
}

// ws layout (bytes)
#define FLAG_OFF    0
#define NTILES_OFF  64
#define TABLE_OFF   1024   // MAX_TILES * int4 (2176 B)
#define TPAD_OFF    8192   // MP_MAX ints (69632 B)
#define WT_OFF      81920  // 16 MB bf16 [E][n][k]
#define XB_OFF      16859136  // 32 MB bf16 [T][k] (fp32 input only)
#define WS_NEED     (16859136UL + (size_t)T_TOK * DIN * 2)

#define TRANS_BLOCKS 512
#define CONV_BLOCKS  1024   // 1024 blk x 1024 thr x 16 elems = 16.78M

// ---- k_front: block 0 = prep+scatter; blocks [1,513) = W transpose;
//      blocks [513, 513+1024) = x fp32 -> bf16 convert (skipped if bf16 in).
__global__ __launch_bounds__(1024) void k_front(
    const unsigned short* __restrict__ xu, const int* __restrict__ idxs,
    const void* __restrict__ Wsrc, short* __restrict__ Wt, short* __restrict__ xb,
    int* __restrict__ flag, int* __restrict__ ntiles,
    int4v* __restrict__ table, int* __restrict__ tpad) {
  __shared__ int fS;
  __shared__ unsigned short tile[128][130];            // transpose path
  __shared__ int wtot[16][NE], waveBase[16][NE];       // prep path
  __shared__ int totS[NE], padS[NE + 1];

  int tid = threadIdx.x;
  // per-block dtype detect: fp32 iff any of first 256 ushorts has "exponent"
  // byte >= 0xC0 (fp32 low-half mantissa bits ~uniform; bf16 N(0,1)
  // exponents ~126 < 0xC0). Zero cross-block dependency.
  if (tid == 0) fS = 0;
  __syncthreads();
  if (tid < 256) {
    int ex = (xu[tid] >> 7) & 0xFF;
    if (ex >= 0xC0) atomicOr(&fS, 1);
  }
  __syncthreads();
  int fp32 = fS;

  if (blockIdx.x >= 1 + TRANS_BLOCKS) {
    // ---- x convert: fp32 -> bf16 into xb ----
    if (!fp32) return;
    int b2 = blockIdx.x - (1 + TRANS_BLOCKS);
    size_t base = ((size_t)b2 * 1024 + tid) * 16;
    const float* src = (const float*)xu + base;
    floatx4 a0 = *(const floatx4*)(src + 0);
    floatx4 a1 = *(const floatx4*)(src + 4);
    floatx4 a2 = *(const floatx4*)(src + 8);
    floatx4 a3 = *(const floatx4*)(src + 12);
    short8 o0, o1;
    #pragma unroll
    for (int j = 0; j < 4; ++j) {
      o0[j] = f2b(a0[j]); o0[4 + j] = f2b(a1[j]);
      o1[j] = f2b(a2[j]); o1[4 + j] = f2b(a3[j]);
    }
    *(short8*)(xb + base) = o0;
    *(short8*)(xb + base + 8) = o1;
    return;
  }

  if (blockIdx.x != 0) {
    // ---- transpose W [E][k][n] -> Wt [E][n][k] bf16, 128x128 region ----
    int b = blockIdx.x - 1;          // [0,512)
    int e = b >> 6, kt = (b >> 3) & 7, nt8 = b & 7;
    size_t ibase = (size_t)e * DIN * DOUT + (size_t)(kt * 128) * DOUT + nt8 * 128;
    int k = tid >> 3, n16 = (tid & 7) * 16;
    if (fp32) {
      const float* p = (const float*)Wsrc + ibase + (size_t)k * DOUT + n16;
      #pragma unroll
      for (int g = 0; g < 4; ++g) {
        floatx4 a = *(const floatx4*)(p + g * 4);
        #pragma unroll
        for (int j = 0; j < 4; ++j) tile[k][n16 + g * 4 + j] = (unsigned short)f2b(a[j]);
      }
    } else {
      const short* p = (const short*)Wsrc + ibase + (size_t)k * DOUT + n16;
      #pragma unroll
      for (int g = 0; g < 2; ++g) {
        short8 v = *(const short8*)(p + g * 8);
        #pragma unroll
        for (int j = 0; j < 8; ++j) tile[k][n16 + g * 8 + j] = (unsigned short)v[j];
      }
    }
    __syncthreads();
    int n = tid >> 3, k16 = (tid & 7) * 16;
    short8 o0, o1;
    #pragma unroll
    for (int j = 0; j < 8; ++j) {
      o0[j] = (short)tile[k16 + j][n];
      o1[j] = (short)tile[k16 + 8 + j][n];
    }
    size_t obase = (size_t)e * DOUT * DIN + (size_t)(nt8 * 128 + n) * DIN + kt * 128 + k16;
    *(short8*)(Wt + obase) = o0;
    *(short8*)(Wt + obase + 8) = o1;
    return;
  }

  // ---- block 0: count -> scan -> table -> scatter -> pad fill ----
  int lane = tid & 63, w = tid >> 6;
  if (tid == 0) *flag = fp32;

  int c[NE];
  #pragma unroll
  for (int e = 0; e < NE; ++e) c[e] = 0;
  const int4v* iv = (const int4v*)idxs;
  int4v vv[4];
  #pragma unroll
  for (int it = 0; it < 4; ++it) {
    vv[it] = iv[tid * 4 + it];
    ++c[vv[it].x]; ++c[vv[it].y]; ++c[vv[it].z]; ++c[vv[it].w];
  }
  // wave-level inclusive scan per expert
  int incl[NE];
  #pragma unroll
  for (int e = 0; e < NE; ++e) {
    incl[e] = c[e];
    #pragma unroll
    for (int d = 1; d < 64; d <<= 1) {
      int o = __shfl_up(incl[e], d);
      if (lane >= d) incl[e] += o;
    }
  }
  if (lane == 63) {
    #pragma unroll
    for (int e = 0; e < NE; ++e) wtot[w][e] = incl[e];
  }
  __syncthreads();
  if (tid < NE) {
    int s = 0;
    for (int ww = 0; ww < 16; ++ww) s += wtot[ww][tid];
    totS[tid] = s;
  }
  __syncthreads();
  if (tid == 0) {
    int p = 0, tc = 0;
    for (int e = 0; e < NE; ++e) {
      padS[e] = p;
      int cn = totS[e];
      int nmt = (cn + BM - 1) >> 7;
      for (int m = 0; m < nmt; ++m) table[tc++] = (int4v){e, p + m * BM, 0, 0};
      p += nmt * BM;
    }
    padS[NE] = p;
    *ntiles = tc;
  }
  __syncthreads();
  if (tid < 128) {
    int ww = tid >> 3, e = tid & 7;
    int s = padS[e];
    for (int wp = 0; wp < ww; ++wp) s += wtot[wp][e];
    waveBase[ww][e] = s;
  }
  __syncthreads();
  // each thread places its 16 tokens at its exclusive-scan base (in order)
  int base[NE];
  #pragma unroll
  for (int e = 0; e < NE; ++e) base[e] = waveBase[w][e] + incl[e] - c[e];
  #pragma unroll
  for (int it = 0; it < 4; ++it) {
    #pragma unroll
    for (int cm = 0; cm < 4; ++cm) {
      int te = vv[it][cm];
      int tk = tid * 16 + it * 4 + cm;
      #pragma unroll
      for (int e0 = 0; e0 < NE; ++e0)
        if (te == e0) tpad[base[e0]++] = tk;   // unrolled const idx: registers
    }
  }
  #pragma unroll
  for (int e = 0; e < NE; ++e) {
    int start = padS[e] + totS[e];
    int len = padS[e + 1] - start;
    if (tid < len) tpad[start + tid] = -1;
  }
}

// ---- GEMM: 128x128 tile, BK=64 (16 iters), single-path bf16, double-
// buffered prefetch (1 barrier per K-step). A gathered per-row from bf16
// source (xb if fp32 input, else x) via per-lane glds addresses;
// XOR-swizzled LDS (16B granule, chunk^(row&7)) -- zero bank conflicts.
#define STAGE(bb, k0)                                                       \
  {                                                                         \
    _Pragma("unroll")                                                       \
    for (int s4 = 0; s4 < 4; ++s4)                                          \
      glds16(bG[s4] + (k0), (char*)lB[bb] + ldsOff[s4]);                    \
    _Pragma("unroll")                                                       \
    for (int s4 = 0; s4 < 4; ++s4)                                          \
      glds16(aG[s4] + (size_t)(k0) * 2, (char*)lA[bb] + ldsOff[s4]);        \
  }

__launch_bounds__(256, 2)
__global__ void k_gemm(const void* __restrict__ xv, const short* __restrict__ xb,
                       const void* __restrict__ bv,
                       const short* __restrict__ Wt, const int* __restrict__ tpad,
                       const int* __restrict__ ntilesp, const int4v* __restrict__ table,
                       const int* __restrict__ flagp, void* __restrict__ outv) {
  int bid = blockIdx.x;
  int xcd = bid & 7;
  int s = bid >> 3;
  int nt = s & 7;                  // 8 n-tiles of 128
  int ti = s >> 3;                 // [0, TPX)
  int t = xcd * TPX + ti;
  if (t >= *ntilesp) return;
  int4v te = table[t];
  int e = te.x, arow0 = te.y;
  int fp32 = *flagp;

  int tid = threadIdx.x;
  int lane = tid & 63;
  int wave = tid >> 6;

  __shared__ short lA[2][BM * BK];   // 2 x 16 KB, swizzled rows of 128B
  __shared__ short lB[2][BN * BK];   // 2 x 16 KB
  __shared__ int tokS[BM];

  if (tid < BM) tokS[tid] = tpad[arow0 + tid];
  __syncthreads();

  const short* WtE = Wt + (size_t)e * DOUT * DIN + (size_t)(nt * BN) * DIN;
  const char* aBase = fp32 ? (const char*)xb : (const char*)xv;  // bf16 rows, 2048 B

  // staging: 1024 16B-units each for A and B; 4/thread.
  // phys chunk p of row r holds logical chunk p^(r&7).
  const char* aG[4];
  const short* bG[4];
  int ldsOff[4];
  #pragma unroll
  for (int s4 = 0; s4 < 4; ++s4) {
    int fl = tid + s4 * 256;
    int r = fl >> 3, p = fl & 7;
    int kc = p ^ (r & 7);
    int tok = tokS[r];
    if (tok < 0) tok = 0;   // pad rows: harmless data, masked at store
    aG[s4] = aBase + (size_t)tok * (DIN * 2) + kc * 16;
    bG[s4] = WtE + (size_t)r * DIN + kc * 8;
    ldsOff[s4] = (s4 * 256 + wave * 64) * 16;
  }

  int wm = wave & 1, wn = wave >> 1;   // 2x2 wave grid, each 64m x 64n
  int lrow = lane & 15, q = lane >> 4;
  // frag reads: logical chunk c = h*4+q of row m -> phys m*BK + (c^(m&7))*8 shorts
  int aOff[4][2], bOff[4][2];
  #pragma unroll
  for (int i = 0; i < 4; ++i) {
    int m = wm * 64 + i * 16 + lrow;
    #pragma unroll
    for (int h = 0; h < 2; ++h)
      aOff[i][h] = m * BK + (((h * 4 + q) ^ (m & 7)) * 8);
  }
  #pragma unroll
  for (int j = 0; j < 4; ++j) {
    int n = wn * 64 + j * 16 + lrow;
    #pragma unroll
    for (int h = 0; h < 2; ++h)
      bOff[j][h] = n * BK + (((h * 4 + q) ^ (n & 7)) * 8);
  }

  floatx4 acc[4][4];
  #pragma unroll
  for (int i = 0; i < 4; ++i)
    #pragma unroll
    for (int j = 0; j < 4; ++j)
      acc[i][j] = (floatx4){0.f, 0.f, 0.f, 0.f};

  // prologue: stage tile 0, drain, sync
  STAGE(0, 0);
  asm volatile("s_waitcnt vmcnt(0)\n\ts_barrier" ::: "memory");

  int cur = 0;
  for (int kt = 0; kt < DIN / BK; ++kt) {
    if (kt < DIN / BK - 1) STAGE(cur ^ 1, (kt + 1) * BK);
    #pragma unroll
    for (int h = 0; h < 2; ++h) {
      short8 af[4], bf[4];
      #pragma unroll
      for (int i = 0; i < 4; ++i) af[i] = *(const short8*)(&lA[cur][0] + aOff[i][h]);
      #pragma unroll
      for (int j = 0; j < 4; ++j) bf[j] = *(const short8*)(&lB[cur][0] + bOff[j][h]);
      // SWAPPED: D[p][c] = sum_k Wt[n-frag p][k] * A[m-frag c][k]
      #pragma unroll
      for (int i = 0; i < 4; ++i)
        #pragma unroll
        for (int j = 0; j < 4; ++j)
          acc[i][j] = __builtin_amdgcn_mfma_f32_16x16x32_bf16(bf[j], af[i], acc[i][j], 0, 0, 0);
    }
    // wait for stage(kt+1) (overlapped with compute above), then sync.
    asm volatile("s_waitcnt vmcnt(0)\n\ts_barrier" ::: "memory");
    cur ^= 1;
  }

  // epilogue: n = nt*128 + wn*64 + j*16 + q*4 + r (regs contiguous in n);
  //           m = wm*64 + i*16 + lrow
  #pragma unroll
  for (int i = 0; i < 4; ++i) {
    int tok = tokS[wm * 64 + i * 16 + lrow];
    if (tok < 0) continue;
    size_t rowb = (size_t)tok * DOUT + nt * BN + wn * 64 + q * 4;
    #pragma unroll
    for (int j = 0; j < 4; ++j) {
      int n = nt * BN + wn * 64 + j * 16 + q * 4;
      if (fp32) {
        floatx4 b4 = *(const floatx4*)((const float*)bv + e * DOUT + n);
        floatx4 o;
        #pragma unroll
        for (int r = 0; r < 4; ++r) {
          float v = acc[i][j][r] + b4[r];
          o[r] = v > 0.f ? v : 0.f;
        }
        *(floatx4*)((float*)outv + rowb + j * 16) = o;
      } else {
        short4v b4 = *(const short4v*)((const short*)bv + e * DOUT + n);
        short4v o;
        #pragma unroll
        for (int r = 0; r < 4; ++r) {
          float v = acc[i][j][r] + b2f((unsigned short)b4[r]);
          o[r] = f2b(v > 0.f ? v : 0.f);
        }
        *(short4v*)((short*)outv + rowb + j * 16) = o;
      }
    }
  }
}

// ---- correct-but-slow fallback if ws too small
__global__ void k_fallback(const void* __restrict__ xv, const int* __restrict__ idxs,
                           const void* __restrict__ Wv, const void* __restrict__ bv,
                           void* __restrict__ outv) {
  __shared__ float xrow[DIN];
  __shared__ int sflag;
  int t = blockIdx.x;
  int e = idxs[t];
  if (threadIdx.x == 0) {
    const unsigned short* u = (const unsigned short*)xv;
    int f = 0;
    for (int i = 0; i < 256; ++i) { int ex = (u[i] >> 7) & 0xFF; if (ex >= 0xC0) f = 1; }
    sflag = f;
  }
  __syncthreads();
  int fp32 = sflag;
  for (int i = threadIdx.x; i < DIN; i += 256)
    xrow[i] = fp32 ? ((const float*)xv)[(size_t)t * DIN + i]
                   : b2f(((const unsigned short*)xv)[(size_t)t * DIN + i]);
  __syncthreads();
  float a[4] = {0.f, 0.f, 0.f, 0.f};
  for (int k = 0; k < DIN; ++k) {
    float xk = xrow[k];
    size_t wb = (size_t)e * DIN * DOUT + (size_t)k * DOUT + threadIdx.x;
    #pragma unroll
    for (int j = 0; j < 4; ++j) {
      float w = fp32 ? ((const float*)Wv)[wb + j * 256]
                     : b2f(((const unsigned short*)Wv)[wb + j * 256]);
      a[j] += xk * w;
    }
  }
  #pragma unroll
  for (int j = 0; j < 4; ++j) {
    int n = threadIdx.x + j * 256;
    float bias = fp32 ? ((const float*)bv)[e * DOUT + n]
                      : b2f(((const unsigned short*)bv)[e * DOUT + n]);
    float v = a[j] + bias;
    v = v > 0.f ? v : 0.f;
    size_t o = (size_t)t * DOUT + n;
    if (fp32) ((float*)outv)[o] = v;
    else      ((short*)outv)[o] = f2b(v);
  }
}

extern "C" void kernel_launch(void* const* d_in, const int* in_sizes, int n_in,
                              void* d_out, int out_size, void* d_ws, size_t ws_size,
                              hipStream_t stream) {
  const void* x    = d_in[0];
  const int*  idxs = (const int*)d_in[1];
  const void* W    = d_in[2];
  const void* bias = d_in[3];

  if (ws_size < WS_NEED) {
    k_fallback<<<T_TOK, 256, 0, stream>>>(x, idxs, W, bias, d_out);
    return;
  }
  char* ws = (char*)d_ws;
  int* flag    = (int*)(ws + FLAG_OFF);
  int* ntiles  = (int*)(ws + NTILES_OFF);
  int4v* table = (int4v*)(ws + TABLE_OFF);
  int* tpad    = (int*)(ws + TPAD_OFF);
  short* Wt    = (short*)(ws + WT_OFF);
  short* xb    = (short*)(ws + XB_OFF);

  k_front<<<1 + TRANS_BLOCKS + CONV_BLOCKS, 1024, 0, stream>>>(
      (const unsigned short*)x, idxs, W, Wt, xb, flag, ntiles, table, tpad);
  k_gemm<<<8 * 8 * TPX, 256, 0, stream>>>(x, xb, bias, Wt, tpad, ntiles, table, flag, d_out);
}

// Round 4
// 212.655 us; speedup vs baseline: 1.0475x; 1.0475x over previous
//
#include <hip/hip_runtime.h>
#include <hip/hip_bf16.h>
#include <stdint.h>

// MoE grouped linear: y[t] = relu(x[t] @ W[idxs[t]] + b[idxs[t]])
// T=16384, D_IN=D_OUT=1024, E=8.
// R10: R9 post-mortem -- dbuf at BK=64 doubled LDS (66KB) and halved
// blocks/CU 4->2; lost the cross-block TLP that was hiding R8's stage drain
// (m132 failure mode). Fix: keep dbuf latency-hiding but hold occupancy:
// BK=32 double-buffered = 2x(8KB A + 8KB B) = 32KB LDS -> 4 blocks/CU
// (same as R8). One fused vmcnt(0)+s_barrier per K-step (32 barriers =
// R8's count), stage(t+1) issued before compute(t), manual x2 unroll so
// buffer index is compile-time. 4-chunk-row swizzle: phys chunk p of row r
// holds logical p^((r>>1)&3); bank-balanced (4 accesses/bank per 32-lane
// phase = b128 structural minimum), staging linear, same involution both
// sides. Front unchanged from R8.

#define T_TOK 16384
#define DIN   1024
#define DOUT  1024
#define NE    8
#define BM    128
#define BN    128
#define BK    32
#define TPX   17                  // A-tiles per XCD slot (8*17 = 136)
#define MAX_TILES 136
#define MP_MAX (T_TOK + NE * BM)  // 17408 padded rows max

typedef __attribute__((ext_vector_type(8))) short short8;
typedef __attribute__((ext_vector_type(4))) short short4v;
typedef __attribute__((ext_vector_type(4))) float floatx4;
typedef __attribute__((ext_vector_type(4))) int int4v;

__device__ __forceinline__ short f2b(float f) {
  return __builtin_bit_cast(short, __float2bfloat16(f));
}
__device__ __forceinline__ float b2f(unsigned short u) {
  unsigned v = ((unsigned)u) << 16;
  return __builtin_bit_cast(float, v);
}
__device__ __forceinline__ void glds16(const void* g, void* l) {
  __builtin_amdgcn_global_load_lds(
      (__attribute__((address_space(1))) void*)g,
      (__attribute__((address_space(3))) void*)l, 16, 0, 0);
}

// ws layout (bytes)
#define FLAG_OFF    0
#define NTILES_OFF  64
#define TABLE_OFF   1024   // MAX_TILES * int4 (2176 B)
#define TPAD_OFF    8192   // MP_MAX ints (69632 B)
#define WT_OFF      81920  // 16 MB bf16 [E][n][k]
#define XB_OFF      16859136  // 32 MB bf16 [T][k] (fp32 input only)
#define WS_NEED     (16859136UL + (size_t)T_TOK * DIN * 2)

#define TRANS_BLOCKS 512
#define CONV_BLOCKS  1024   // 1024 blk x 1024 thr x 16 elems = 16.78M

// ---- k_front: block 0 = prep+scatter; blocks [1,513) = W transpose;
//      blocks [513, 513+1024) = x fp32 -> bf16 convert (skipped if bf16 in).
__global__ __launch_bounds__(1024) void k_front(
    const unsigned short* __restrict__ xu, const int* __restrict__ idxs,
    const void* __restrict__ Wsrc, short* __restrict__ Wt, short* __restrict__ xb,
    int* __restrict__ flag, int* __restrict__ ntiles,
    int4v* __restrict__ table, int* __restrict__ tpad) {
  __shared__ int fS;
  __shared__ unsigned short tile[128][130];            // transpose path
  __shared__ int wtot[16][NE], waveBase[16][NE];       // prep path
  __shared__ int totS[NE], padS[NE + 1];

  int tid = threadIdx.x;
  // per-block dtype detect: fp32 iff any of first 256 ushorts has "exponent"
  // byte >= 0xC0 (fp32 low-half mantissa bits ~uniform; bf16 N(0,1)
  // exponents ~126 < 0xC0). Zero cross-block dependency.
  if (tid == 0) fS = 0;
  __syncthreads();
  if (tid < 256) {
    int ex = (xu[tid] >> 7) & 0xFF;
    if (ex >= 0xC0) atomicOr(&fS, 1);
  }
  __syncthreads();
  int fp32 = fS;

  if (blockIdx.x >= 1 + TRANS_BLOCKS) {
    // ---- x convert: fp32 -> bf16 into xb ----
    if (!fp32) return;
    int b2 = blockIdx.x - (1 + TRANS_BLOCKS);
    size_t base = ((size_t)b2 * 1024 + tid) * 16;
    const float* src = (const float*)xu + base;
    floatx4 a0 = *(const floatx4*)(src + 0);
    floatx4 a1 = *(const floatx4*)(src + 4);
    floatx4 a2 = *(const floatx4*)(src + 8);
    floatx4 a3 = *(const floatx4*)(src + 12);
    short8 o0, o1;
    #pragma unroll
    for (int j = 0; j < 4; ++j) {
      o0[j] = f2b(a0[j]); o0[4 + j] = f2b(a1[j]);
      o1[j] = f2b(a2[j]); o1[4 + j] = f2b(a3[j]);
    }
    *(short8*)(xb + base) = o0;
    *(short8*)(xb + base + 8) = o1;
    return;
  }

  if (blockIdx.x != 0) {
    // ---- transpose W [E][k][n] -> Wt [E][n][k] bf16, 128x128 region ----
    int b = blockIdx.x - 1;          // [0,512)
    int e = b >> 6, kt = (b >> 3) & 7, nt8 = b & 7;
    size_t ibase = (size_t)e * DIN * DOUT + (size_t)(kt * 128) * DOUT + nt8 * 128;
    int k = tid >> 3, n16 = (tid & 7) * 16;
    if (fp32) {
      const float* p = (const float*)Wsrc + ibase + (size_t)k * DOUT + n16;
      #pragma unroll
      for (int g = 0; g < 4; ++g) {
        floatx4 a = *(const floatx4*)(p + g * 4);
        #pragma unroll
        for (int j = 0; j < 4; ++j) tile[k][n16 + g * 4 + j] = (unsigned short)f2b(a[j]);
      }
    } else {
      const short* p = (const short*)Wsrc + ibase + (size_t)k * DOUT + n16;
      #pragma unroll
      for (int g = 0; g < 2; ++g) {
        short8 v = *(const short8*)(p + g * 8);
        #pragma unroll
        for (int j = 0; j < 8; ++j) tile[k][n16 + g * 8 + j] = (unsigned short)v[j];
      }
    }
    __syncthreads();
    int n = tid >> 3, k16 = (tid & 7) * 16;
    short8 o0, o1;
    #pragma unroll
    for (int j = 0; j < 8; ++j) {
      o0[j] = (short)tile[k16 + j][n];
      o1[j] = (short)tile[k16 + 8 + j][n];
    }
    size_t obase = (size_t)e * DOUT * DIN + (size_t)(nt8 * 128 + n) * DIN + kt * 128 + k16;
    *(short8*)(Wt + obase) = o0;
    *(short8*)(Wt + obase + 8) = o1;
    return;
  }

  // ---- block 0: count -> scan -> table -> scatter -> pad fill ----
  int lane = tid & 63, w = tid >> 6;
  if (tid == 0) *flag = fp32;

  int c[NE];
  #pragma unroll
  for (int e = 0; e < NE; ++e) c[e] = 0;
  const int4v* iv = (const int4v*)idxs;
  int4v vv[4];
  #pragma unroll
  for (int it = 0; it < 4; ++it) {
    vv[it] = iv[tid * 4 + it];
    ++c[vv[it].x]; ++c[vv[it].y]; ++c[vv[it].z]; ++c[vv[it].w];
  }
  // wave-level inclusive scan per expert
  int incl[NE];
  #pragma unroll
  for (int e = 0; e < NE; ++e) {
    incl[e] = c[e];
    #pragma unroll
    for (int d = 1; d < 64; d <<= 1) {
      int o = __shfl_up(incl[e], d);
      if (lane >= d) incl[e] += o;
    }
  }
  if (lane == 63) {
    #pragma unroll
    for (int e = 0; e < NE; ++e) wtot[w][e] = incl[e];
  }
  __syncthreads();
  if (tid < NE) {
    int s = 0;
    for (int ww = 0; ww < 16; ++ww) s += wtot[ww][tid];
    totS[tid] = s;
  }
  __syncthreads();
  if (tid == 0) {
    int p = 0, tc = 0;
    for (int e = 0; e < NE; ++e) {
      padS[e] = p;
      int cn = totS[e];
      int nmt = (cn + BM - 1) >> 7;
      for (int m = 0; m < nmt; ++m) table[tc++] = (int4v){e, p + m * BM, 0, 0};
      p += nmt * BM;
    }
    padS[NE] = p;
    *ntiles = tc;
  }
  __syncthreads();
  if (tid < 128) {
    int ww = tid >> 3, e = tid & 7;
    int s = padS[e];
    for (int wp = 0; wp < ww; ++wp) s += wtot[wp][e];
    waveBase[ww][e] = s;
  }
  __syncthreads();
  // each thread places its 16 tokens at its exclusive-scan base (in order)
  int base[NE];
  #pragma unroll
  for (int e = 0; e < NE; ++e) base[e] = waveBase[w][e] + incl[e] - c[e];
  #pragma unroll
  for (int it = 0; it < 4; ++it) {
    #pragma unroll
    for (int cm = 0; cm < 4; ++cm) {
      int te = vv[it][cm];
      int tk = tid * 16 + it * 4 + cm;
      #pragma unroll
      for (int e0 = 0; e0 < NE; ++e0)
        if (te == e0) tpad[base[e0]++] = tk;   // unrolled const idx: registers
    }
  }
  #pragma unroll
  for (int e = 0; e < NE; ++e) {
    int start = padS[e] + totS[e];
    int len = padS[e + 1] - start;
    if (tid < len) tpad[start + tid] = -1;
  }
}

// ---- GEMM: 128x128 tile, BK=32 (32 K-steps), double-buffered (32KB LDS,
// 4 blocks/CU), one vmcnt(0)+s_barrier per K-step. A gathered per-row from
// bf16 source (xb if fp32 input, else x) via per-lane glds addresses.
// Swizzle: rows of 64B = 4 chunks(16B); phys chunk p of row r holds logical
// p^((r>>1)&3). Fragment read: logical chunk q=lane>>4 of row m at phys
// m*BK + (q^((m>>1)&3))*8 shorts -> 4 accesses/bank per 32-lane phase
// (b128 structural minimum, no extra conflict).
#define STAGE(NXT, k0)                                                      \
  {                                                                         \
    _Pragma("unroll")                                                       \
    for (int s4 = 0; s4 < 2; ++s4)                                          \
      glds16(bG[s4] + (k0), (char*)(lBbuf + (NXT) * (BN * BK)) + ldsOff[s4]); \
    _Pragma("unroll")                                                       \
    for (int s4 = 0; s4 < 2; ++s4)                                          \
      glds16(aG[s4] + (size_t)(k0) * 2, (char*)(lAbuf + (NXT) * (BM * BK)) + ldsOff[s4]); \
  }

#define KSTEP(CUR, NXT, kNext, DO_STAGE)                                    \
  {                                                                         \
    if (DO_STAGE) STAGE(NXT, kNext);                                        \
    short8 af[4], bf[4];                                                    \
    _Pragma("unroll")                                                       \
    for (int i = 0; i < 4; ++i)                                             \
      af[i] = *(const short8*)(lAbuf + (CUR) * (BM * BK) + aOff[i]);        \
    _Pragma("unroll")                                                       \
    for (int j = 0; j < 4; ++j)                                             \
      bf[j] = *(const short8*)(lBbuf + (CUR) * (BN * BK) + bOff[j]);        \
    _Pragma("unroll")                                                       \
    for (int i = 0; i < 4; ++i)                                             \
      _Pragma("unroll")                                                     \
      for (int j = 0; j < 4; ++j)                                           \
        acc[i][j] = __builtin_amdgcn_mfma_f32_16x16x32_bf16(bf[j], af[i], acc[i][j], 0, 0, 0); \
    asm volatile("s_waitcnt vmcnt(0)\n\ts_barrier" ::: "memory");           \
  }

__launch_bounds__(256, 4)
__global__ void k_gemm(const void* __restrict__ xv, const short* __restrict__ xb,
                       const void* __restrict__ bv,
                       const short* __restrict__ Wt, const int* __restrict__ tpad,
                       const int* __restrict__ ntilesp, const int4v* __restrict__ table,
                       const int* __restrict__ flagp, void* __restrict__ outv) {
  int bid = blockIdx.x;
  int xcd = bid & 7;
  int s = bid >> 3;
  int nt = s & 7;                  // 8 n-tiles of 128
  int ti = s >> 3;                 // [0, TPX)
  int t = xcd * TPX + ti;
  if (t >= *ntilesp) return;
  int4v te = table[t];
  int e = te.x, arow0 = te.y;
  int fp32 = *flagp;

  int tid = threadIdx.x;
  int lane = tid & 63;
  int wave = tid >> 6;

  __shared__ short lAbuf[2 * BM * BK];   // 2 x 8 KB, swizzled rows of 64B
  __shared__ short lBbuf[2 * BN * BK];   // 2 x 8 KB
  __shared__ int tokS[BM];

  if (tid < BM) tokS[tid] = tpad[arow0 + tid];
  __syncthreads();

  const short* WtE = Wt + (size_t)e * DOUT * DIN + (size_t)(nt * BN) * DIN;
  const char* aBase = fp32 ? (const char*)xb : (const char*)xv;  // bf16 rows, 2048 B

  // staging: 512 16B-units each for A and B; 2/thread.
  // phys chunk p (of 4) of row r holds logical chunk p^((r>>1)&3).
  const char* aG[2];
  const short* bG[2];
  int ldsOff[2];
  #pragma unroll
  for (int s4 = 0; s4 < 2; ++s4) {
    int fl = tid + s4 * 256;       // [0,512)
    int r = fl >> 2, p = fl & 3;
    int kc = p ^ ((r >> 1) & 3);
    int tok = tokS[r];
    if (tok < 0) tok = 0;   // pad rows: harmless data, masked at store
    aG[s4] = aBase + (size_t)tok * (DIN * 2) + kc * 16;
    bG[s4] = WtE + (size_t)r * DIN + kc * 8;
    ldsOff[s4] = (s4 * 256 + wave * 64) * 16;
  }

  int wm = wave & 1, wn = wave >> 1;   // 2x2 wave grid, each 64m x 64n
  int lrow = lane & 15, q = lane >> 4; // q = logical k-chunk (K=32 -> 4 chunks)
  int aOff[4], bOff[4];
  #pragma unroll
  for (int i = 0; i < 4; ++i) {
    int m = wm * 64 + i * 16 + lrow;
    aOff[i] = m * BK + ((q ^ ((m >> 1) & 3)) * 8);
  }
  #pragma unroll
  for (int j = 0; j < 4; ++j) {
    int n = wn * 64 + j * 16 + lrow;
    bOff[j] = n * BK + ((q ^ ((n >> 1) & 3)) * 8);
  }

  floatx4 acc[4][4];
  #pragma unroll
  for (int i = 0; i < 4; ++i)
    #pragma unroll
    for (int j = 0; j < 4; ++j)
      acc[i][j] = (floatx4){0.f, 0.f, 0.f, 0.f};

  // prologue: stage tile 0 into buf0, drain, sync
  STAGE(0, 0);
  asm volatile("s_waitcnt vmcnt(0)\n\ts_barrier" ::: "memory");

  // 32 K-steps, manually unrolled x2 so buffer index is compile-time.
  for (int kt = 0; kt < DIN / BK; kt += 2) {
    KSTEP(0, 1, (kt + 1) * BK, true);
    KSTEP(1, 0, (kt + 2) * BK, (kt + 2) < DIN / BK);
  }

  // epilogue: n = nt*128 + wn*64 + j*16 + q*4 + r (regs contiguous in n);
  //           m = wm*64 + i*16 + lrow
  #pragma unroll
  for (int i = 0; i < 4; ++i) {
    int tok = tokS[wm * 64 + i * 16 + lrow];
    if (tok < 0) continue;
    size_t rowb = (size_t)tok * DOUT + nt * BN + wn * 64 + q * 4;
    #pragma unroll
    for (int j = 0; j < 4; ++j) {
      int n = nt * BN + wn * 64 + j * 16 + q * 4;
      if (fp32) {
        floatx4 b4 = *(const floatx4*)((const float*)bv + e * DOUT + n);
        floatx4 o;
        #pragma unroll
        for (int r = 0; r < 4; ++r) {
          float v = acc[i][j][r] + b4[r];
          o[r] = v > 0.f ? v : 0.f;
        }
        *(floatx4*)((float*)outv + rowb + j * 16) = o;
      } else {
        short4v b4 = *(const short4v*)((const short*)bv + e * DOUT + n);
        short4v o;
        #pragma unroll
        for (int r = 0; r < 4; ++r) {
          float v = acc[i][j][r] + b2f((unsigned short)b4[r]);
          o[r] = f2b(v > 0.f ? v : 0.f);
        }
        *(short4v*)((short*)outv + rowb + j * 16) = o;
      }
    }
  }
}

// ---- correct-but-slow fallback if ws too small
__global__ void k_fallback(const void* __restrict__ xv, const int* __restrict__ idxs,
                           const void* __restrict__ Wv, const void* __restrict__ bv,
                           void* __restrict__ outv) {
  __shared__ float xrow[DIN];
  __shared__ int sflag;
  int t = blockIdx.x;
  int e = idxs[t];
  if (threadIdx.x == 0) {
    const unsigned short* u = (const unsigned short*)xv;
    int f = 0;
    for (int i = 0; i < 256; ++i) { int ex = (u[i] >> 7) & 0xFF; if (ex >= 0xC0) f = 1; }
    sflag = f;
  }
  __syncthreads();
  int fp32 = sflag;
  for (int i = threadIdx.x; i < DIN; i += 256)
    xrow[i] = fp32 ? ((const float*)xv)[(size_t)t * DIN + i]
                   : b2f(((const unsigned short*)xv)[(size_t)t * DIN + i]);
  __syncthreads();
  float a[4] = {0.f, 0.f, 0.f, 0.f};
  for (int k = 0; k < DIN; ++k) {
    float xk = xrow[k];
    size_t wb = (size_t)e * DIN * DOUT + (size_t)k * DOUT + threadIdx.x;
    #pragma unroll
    for (int j = 0; j < 4; ++j) {
      float w = fp32 ? ((const float*)Wv)[wb + j * 256]
                     : b2f(((const unsigned short*)Wv)[wb + j * 256]);
      a[j] += xk * w;
    }
  }
  #pragma unroll
  for (int j = 0; j < 4; ++j) {
    int n = threadIdx.x + j * 256;
    float bias = fp32 ? ((const float*)bv)[e * DOUT + n]
                      : b2f(((const unsigned short*)bv)[e * DOUT + n]);
    float v = a[j] + bias;
    v = v > 0.f ? v : 0.f;
    size_t o = (size_t)t * DOUT + n;
    if (fp32) ((float*)outv)[o] = v;
    else      ((short*)outv)[o] = f2b(v);
  }
}

extern "C" void kernel_launch(void* const* d_in, const int* in_sizes, int n_in,
                              void* d_out, int out_size, void* d_ws, size_t ws_size,
                              hipStream_t stream) {
  const void* x    = d_in[0];
  const int*  idxs = (const int*)d_in[1];
  const void* W    = d_in[2];
  const void* bias = d_in[3];

  if (ws_size < WS_NEED) {
    k_fallback<<<T_TOK, 256, 0, stream>>>(x, idxs, W, bias, d_out);
    return;
  }
  char* ws = (char*)d_ws;
  int* flag    = (int*)(ws + FLAG_OFF);
  int* ntiles  = (int*)(ws + NTILES_OFF);
  int4v* table = (int4v*)(ws + TABLE_OFF);
  int* tpad    = (int*)(ws + TPAD_OFF);
  short* Wt    = (short*)(ws + WT_OFF);
  short* xb    = (short*)(ws + XB_OFF);

  k_front<<<1 + TRANS_BLOCKS + CONV_BLOCKS, 1024, 0, stream>>>(
      (const unsigned short*)x, idxs, W, Wt, xb, flag, ntiles, table, tpad);
  k_gemm<<<8 * 8 * TPX, 256, 0, stream>>>(x, xb, bias, Wt, tpad, ntiles, table, flag, d_out);
}

// Round 5
// 200.574 us; speedup vs baseline: 1.1106x; 1.0602x over previous
//
#include <hip/hip_runtime.h>
#include <hip/hip_bf16.h>
#include <stdint.h>

// MoE grouped linear: y[t] = relu(x[t] @ W[idxs[t]] + b[idxs[t]])
// T=16384, D_IN=D_OUT=1024, E=8.
// R11: consolidation. R9 (dbuf BK=64) and R10 (dbuf BK=32) both lost to R8's
// plain 2-barrier loop: pipelining variants all bust either the LDS budget
// (blocks/CU 4->2) or the 128-register occupancy quantum (R8 = 60 VGPR + 64
// AGPR = 124, four under the step). Counted-vmcnt needs drain->barrier->read
// (cross-wave LDS visibility) = 2 barriers/step at BK=32 = no net win.
// 8-phase 256-class tiles quantize to 272/544 blocks -> 50-70% CU util on
// this shape. So: gemm reverted to R8 verbatim (measured 58us, structure
// plateau ~= m233's 607 TF 2-phase datum). Front: transpose LDS writes
// vectorized (16 scalar u16 -> 2x b128, tile stride 130->136 shorts for
// 16B alignment).

#define T_TOK 16384
#define DIN   1024
#define DOUT  1024
#define NE    8
#define BM    128
#define BN    128
#define BK    64
#define TPX   17                  // A-tiles per XCD slot (8*17 = 136)
#define MAX_TILES 136
#define MP_MAX (T_TOK + NE * BM)  // 17408 padded rows max

typedef __attribute__((ext_vector_type(8))) short short8;
typedef __attribute__((ext_vector_type(4))) short short4v;
typedef __attribute__((ext_vector_type(4))) float floatx4;
typedef __attribute__((ext_vector_type(4))) int int4v;

__device__ __forceinline__ short f2b(float f) {
  return __builtin_bit_cast(short, __float2bfloat16(f));
}
__device__ __forceinline__ float b2f(unsigned short u) {
  unsigned v = ((unsigned)u) << 16;
  return __builtin_bit_cast(float, v);
}
__device__ __forceinline__ void glds16(const void* g, void* l) {
  __builtin_amdgcn_global_load_lds(
      (__attribute__((address_space(1))) void*)g,
      (__attribute__((address_space(3))) void*)l, 16, 0, 0);
}

// ws layout (bytes)
#define FLAG_OFF    0
#define NTILES_OFF  64
#define TABLE_OFF   1024   // MAX_TILES * int4 (2176 B)
#define TPAD_OFF    8192   // MP_MAX ints (69632 B)
#define WT_OFF      81920  // 16 MB bf16 [E][n][k]
#define XB_OFF      16859136  // 32 MB bf16 [T][k] (fp32 input only)
#define WS_NEED     (16859136UL + (size_t)T_TOK * DIN * 2)

#define TRANS_BLOCKS 512
#define CONV_BLOCKS  1024   // 1024 blk x 1024 thr x 16 elems = 16.78M

// ---- k_front: block 0 = prep+scatter; blocks [1,513) = W transpose;
//      blocks [513, 513+1024) = x fp32 -> bf16 convert (skipped if bf16 in).
__global__ __launch_bounds__(1024) void k_front(
    const unsigned short* __restrict__ xu, const int* __restrict__ idxs,
    const void* __restrict__ Wsrc, short* __restrict__ Wt, short* __restrict__ xb,
    int* __restrict__ flag, int* __restrict__ ntiles,
    int4v* __restrict__ table, int* __restrict__ tpad) {
  __shared__ int fS;
  __shared__ unsigned short tile[128][136];            // transpose path (16B-aligned rows)
  __shared__ int wtot[16][NE], waveBase[16][NE];       // prep path
  __shared__ int totS[NE], padS[NE + 1];

  int tid = threadIdx.x;
  // per-block dtype detect: fp32 iff any of first 256 ushorts has "exponent"
  // byte >= 0xC0 (fp32 low-half mantissa bits ~uniform; bf16 N(0,1)
  // exponents ~126 < 0xC0). Zero cross-block dependency.
  if (tid == 0) fS = 0;
  __syncthreads();
  if (tid < 256) {
    int ex = (xu[tid] >> 7) & 0xFF;
    if (ex >= 0xC0) atomicOr(&fS, 1);
  }
  __syncthreads();
  int fp32 = fS;

  if (blockIdx.x >= 1 + TRANS_BLOCKS) {
    // ---- x convert: fp32 -> bf16 into xb ----
    if (!fp32) return;
    int b2 = blockIdx.x - (1 + TRANS_BLOCKS);
    size_t base = ((size_t)b2 * 1024 + tid) * 16;
    const float* src = (const float*)xu + base;
    floatx4 a0 = *(const floatx4*)(src + 0);
    floatx4 a1 = *(const floatx4*)(src + 4);
    floatx4 a2 = *(const floatx4*)(src + 8);
    floatx4 a3 = *(const floatx4*)(src + 12);
    short8 o0, o1;
    #pragma unroll
    for (int j = 0; j < 4; ++j) {
      o0[j] = f2b(a0[j]); o0[4 + j] = f2b(a1[j]);
      o1[j] = f2b(a2[j]); o1[4 + j] = f2b(a3[j]);
    }
    *(short8*)(xb + base) = o0;
    *(short8*)(xb + base + 8) = o1;
    return;
  }

  if (blockIdx.x != 0) {
    // ---- transpose W [E][k][n] -> Wt [E][n][k] bf16, 128x128 region ----
    int b = blockIdx.x - 1;          // [0,512)
    int e = b >> 6, kt = (b >> 3) & 7, nt8 = b & 7;
    size_t ibase = (size_t)e * DIN * DOUT + (size_t)(kt * 128) * DOUT + nt8 * 128;
    int k = tid >> 3, n16 = (tid & 7) * 16;
    short8 w0, w1;
    if (fp32) {
      const float* p = (const float*)Wsrc + ibase + (size_t)k * DOUT + n16;
      floatx4 a0 = *(const floatx4*)(p + 0);
      floatx4 a1 = *(const floatx4*)(p + 4);
      floatx4 a2 = *(const floatx4*)(p + 8);
      floatx4 a3 = *(const floatx4*)(p + 12);
      #pragma unroll
      for (int j = 0; j < 4; ++j) {
        w0[j] = f2b(a0[j]); w0[4 + j] = f2b(a1[j]);
        w1[j] = f2b(a2[j]); w1[4 + j] = f2b(a3[j]);
      }
    } else {
      const short* p = (const short*)Wsrc + ibase + (size_t)k * DOUT + n16;
      w0 = *(const short8*)(p + 0);
      w1 = *(const short8*)(p + 8);
    }
    // vectorized LDS writes: rows are 136 shorts (272 B, 16B-aligned);
    // n16*2 is 32B-aligned -> both short8 stores are 16B-aligned.
    *(short8*)(&tile[k][n16])     = w0;
    *(short8*)(&tile[k][n16 + 8]) = w1;
    __syncthreads();
    int n = tid >> 3, k16 = (tid & 7) * 16;
    short8 o0, o1;
    #pragma unroll
    for (int j = 0; j < 8; ++j) {
      o0[j] = (short)tile[k16 + j][n];
      o1[j] = (short)tile[k16 + 8 + j][n];
    }
    size_t obase = (size_t)e * DOUT * DIN + (size_t)(nt8 * 128 + n) * DIN + kt * 128 + k16;
    *(short8*)(Wt + obase) = o0;
    *(short8*)(Wt + obase + 8) = o1;
    return;
  }

  // ---- block 0: count -> scan -> table -> scatter -> pad fill ----
  int lane = tid & 63, w = tid >> 6;
  if (tid == 0) *flag = fp32;

  int c[NE];
  #pragma unroll
  for (int e = 0; e < NE; ++e) c[e] = 0;
  const int4v* iv = (const int4v*)idxs;
  int4v vv[4];
  #pragma unroll
  for (int it = 0; it < 4; ++it) {
    vv[it] = iv[tid * 4 + it];
    ++c[vv[it].x]; ++c[vv[it].y]; ++c[vv[it].z]; ++c[vv[it].w];
  }
  // wave-level inclusive scan per expert
  int incl[NE];
  #pragma unroll
  for (int e = 0; e < NE; ++e) {
    incl[e] = c[e];
    #pragma unroll
    for (int d = 1; d < 64; d <<= 1) {
      int o = __shfl_up(incl[e], d);
      if (lane >= d) incl[e] += o;
    }
  }
  if (lane == 63) {
    #pragma unroll
    for (int e = 0; e < NE; ++e) wtot[w][e] = incl[e];
  }
  __syncthreads();
  if (tid < NE) {
    int s = 0;
    for (int ww = 0; ww < 16; ++ww) s += wtot[ww][tid];
    totS[tid] = s;
  }
  __syncthreads();
  if (tid == 0) {
    int p = 0, tc = 0;
    for (int e = 0; e < NE; ++e) {
      padS[e] = p;
      int cn = totS[e];
      int nmt = (cn + BM - 1) >> 7;
      for (int m = 0; m < nmt; ++m) table[tc++] = (int4v){e, p + m * BM, 0, 0};
      p += nmt * BM;
    }
    padS[NE] = p;
    *ntiles = tc;
  }
  __syncthreads();
  if (tid < 128) {
    int ww = tid >> 3, e = tid & 7;
    int s = padS[e];
    for (int wp = 0; wp < ww; ++wp) s += wtot[wp][e];
    waveBase[ww][e] = s;
  }
  __syncthreads();
  // each thread places its 16 tokens at its exclusive-scan base (in order)
  int base[NE];
  #pragma unroll
  for (int e = 0; e < NE; ++e) base[e] = waveBase[w][e] + incl[e] - c[e];
  #pragma unroll
  for (int it = 0; it < 4; ++it) {
    #pragma unroll
    for (int cm = 0; cm < 4; ++cm) {
      int te = vv[it][cm];
      int tk = tid * 16 + it * 4 + cm;
      #pragma unroll
      for (int e0 = 0; e0 < NE; ++e0)
        if (te == e0) tpad[base[e0]++] = tk;   // unrolled const idx: registers
    }
  }
  #pragma unroll
  for (int e = 0; e < NE; ++e) {
    int start = padS[e] + totS[e];
    int len = padS[e + 1] - start;
    if (tid < len) tpad[start + tid] = -1;
  }
}

// ---- GEMM (R8 verbatim): 128x128 tile, BK=64 (16 iters), single-path bf16.
// A gathered per-row from bf16 source (xb if fp32 input, else x itself)
// via per-lane glds addresses; XOR-swizzled LDS (16B granule, chunk^(row&7))
// -- measured zero bank conflicts. Operand-swapped MFMA epilogue.
// 60 VGPR + 64 AGPR = 124 total: 4 under the 128 occupancy quantum ->
// 4 waves/SIMD capacity. Do not add register state to this kernel.
__launch_bounds__(256, 4)
__global__ void k_gemm(const void* __restrict__ xv, const short* __restrict__ xb,
                       const void* __restrict__ bv,
                       const short* __restrict__ Wt, const int* __restrict__ tpad,
                       const int* __restrict__ ntilesp, const int4v* __restrict__ table,
                       const int* __restrict__ flagp, void* __restrict__ outv) {
  int bid = blockIdx.x;
  int xcd = bid & 7;
  int s = bid >> 3;
  int nt = s & 7;                  // 8 n-tiles of 128
  int ti = s >> 3;                 // [0, TPX)
  int t = xcd * TPX + ti;
  if (t >= *ntilesp) return;
  int4v te = table[t];
  int e = te.x, arow0 = te.y;
  int fp32 = *flagp;

  int tid = threadIdx.x;
  int lane = tid & 63;
  int wave = tid >> 6;

  __shared__ short lA[BM * BK];   // 16 KB, rows of 128B (8 chunks), swizzled
  __shared__ short lB[BN * BK];   // 16 KB
  __shared__ int tokS[BM];

  if (tid < BM) tokS[tid] = tpad[arow0 + tid];
  __syncthreads();

  const short* WtE = Wt + (size_t)e * DOUT * DIN + (size_t)(nt * BN) * DIN;
  const char* aBase = fp32 ? (const char*)xb : (const char*)xv;  // bf16 rows, 2048 B

  // staging: 1024 16B-units each for A and B; 4/thread.
  // phys chunk p of row r holds logical chunk p^(r&7).
  const char* aG[4];
  const short* bG[4];
  char *aL[4], *bL[4];
  #pragma unroll
  for (int s4 = 0; s4 < 4; ++s4) {
    int fl = tid + s4 * 256;
    int r = fl >> 3, p = fl & 7;
    int kc = p ^ (r & 7);
    int tok = tokS[r];
    if (tok < 0) tok = 0;   // pad rows: harmless data, masked at store
    aG[s4] = aBase + (size_t)tok * (DIN * 2) + kc * 16;
    aL[s4] = (char*)lA + (s4 * 256 + wave * 64) * 16;
    bG[s4] = WtE + (size_t)r * DIN + kc * 8;
    bL[s4] = (char*)lB + (s4 * 256 + wave * 64) * 16;
  }

  int wm = wave & 1, wn = wave >> 1;   // 2x2 wave grid, each 64m x 64n
  int lrow = lane & 15, q = lane >> 4;
  // frag reads: logical chunk c = h*4+q of row m -> phys m*BK + (c^(m&7))*8 shorts
  int aOff[4][2], bOff[4][2];
  #pragma unroll
  for (int i = 0; i < 4; ++i) {
    int m = wm * 64 + i * 16 + lrow;
    #pragma unroll
    for (int h = 0; h < 2; ++h)
      aOff[i][h] = m * BK + (((h * 4 + q) ^ (m & 7)) * 8);
  }
  #pragma unroll
  for (int j = 0; j < 4; ++j) {
    int n = wn * 64 + j * 16 + lrow;
    #pragma unroll
    for (int h = 0; h < 2; ++h)
      bOff[j][h] = n * BK + (((h * 4 + q) ^ (n & 7)) * 8);
  }

  floatx4 acc[4][4];
  #pragma unroll
  for (int i = 0; i < 4; ++i)
    #pragma unroll
    for (int j = 0; j < 4; ++j)
      acc[i][j] = (floatx4){0.f, 0.f, 0.f, 0.f};

  for (int k0 = 0; k0 < DIN; k0 += BK) {
    __syncthreads();
    #pragma unroll
    for (int s4 = 0; s4 < 4; ++s4) glds16(bG[s4] + k0, bL[s4]);
    #pragma unroll
    for (int s4 = 0; s4 < 4; ++s4) glds16(aG[s4] + k0 * 2, aL[s4]);
    __syncthreads();
    #pragma unroll
    for (int h = 0; h < 2; ++h) {
      short8 af[4], bf[4];
      #pragma unroll
      for (int i = 0; i < 4; ++i) af[i] = *(const short8*)(lA + aOff[i][h]);
      #pragma unroll
      for (int j = 0; j < 4; ++j) bf[j] = *(const short8*)(lB + bOff[j][h]);
      // SWAPPED: D[p][c] = sum_k Wt[n-frag p][k] * A[m-frag c][k]
      #pragma unroll
      for (int i = 0; i < 4; ++i)
        #pragma unroll
        for (int j = 0; j < 4; ++j)
          acc[i][j] = __builtin_amdgcn_mfma_f32_16x16x32_bf16(bf[j], af[i], acc[i][j], 0, 0, 0);
    }
  }

  // epilogue: n = nt*128 + wn*64 + j*16 + q*4 + r (regs contiguous in n);
  //           m = wm*64 + i*16 + lrow
  #pragma unroll
  for (int i = 0; i < 4; ++i) {
    int tok = tokS[wm * 64 + i * 16 + lrow];
    if (tok < 0) continue;
    size_t rowb = (size_t)tok * DOUT + nt * BN + wn * 64 + q * 4;
    #pragma unroll
    for (int j = 0; j < 4; ++j) {
      int n = nt * BN + wn * 64 + j * 16 + q * 4;
      if (fp32) {
        floatx4 b4 = *(const floatx4*)((const float*)bv + e * DOUT + n);
        floatx4 o;
        #pragma unroll
        for (int r = 0; r < 4; ++r) {
          float v = acc[i][j][r] + b4[r];
          o[r] = v > 0.f ? v : 0.f;
        }
        *(floatx4*)((float*)outv + rowb + j * 16) = o;
      } else {
        short4v b4 = *(const short4v*)((const short*)bv + e * DOUT + n);
        short4v o;
        #pragma unroll
        for (int r = 0; r < 4; ++r) {
          float v = acc[i][j][r] + b2f((unsigned short)b4[r]);
          o[r] = f2b(v > 0.f ? v : 0.f);
        }
        *(short4v*)((short*)outv + rowb + j * 16) = o;
      }
    }
  }
}

// ---- correct-but-slow fallback if ws too small
__global__ void k_fallback(const void* __restrict__ xv, const int* __restrict__ idxs,
                           const void* __restrict__ Wv, const void* __restrict__ bv,
                           void* __restrict__ outv) {
  __shared__ float xrow[DIN];
  __shared__ int sflag;
  int t = blockIdx.x;
  int e = idxs[t];
  if (threadIdx.x == 0) {
    const unsigned short* u = (const unsigned short*)xv;
    int f = 0;
    for (int i = 0; i < 256; ++i) { int ex = (u[i] >> 7) & 0xFF; if (ex >= 0xC0) f = 1; }
    sflag = f;
  }
  __syncthreads();
  int fp32 = sflag;
  for (int i = threadIdx.x; i < DIN; i += 256)
    xrow[i] = fp32 ? ((const float*)xv)[(size_t)t * DIN + i]
                   : b2f(((const unsigned short*)xv)[(size_t)t * DIN + i]);
  __syncthreads();
  float a[4] = {0.f, 0.f, 0.f, 0.f};
  for (int k = 0; k < DIN; ++k) {
    float xk = xrow[k];
    size_t wb = (size_t)e * DIN * DOUT + (size_t)k * DOUT + threadIdx.x;
    #pragma unroll
    for (int j = 0; j < 4; ++j) {
      float w = fp32 ? ((const float*)Wv)[wb + j * 256]
                     : b2f(((const unsigned short*)Wv)[wb + j * 256]);
      a[j] += xk * w;
    }
  }
  #pragma unroll
  for (int j = 0; j < 4; ++j) {
    int n = threadIdx.x + j * 256;
    float bias = fp32 ? ((const float*)bv)[e * DOUT + n]
                      : b2f(((const unsigned short*)bv)[e * DOUT + n]);
    float v = a[j] + bias;
    v = v > 0.f ? v : 0.f;
    size_t o = (size_t)t * DOUT + n;
    if (fp32) ((float*)outv)[o] = v;
    else      ((short*)outv)[o] = f2b(v);
  }
}

extern "C" void kernel_launch(void* const* d_in, const int* in_sizes, int n_in,
                              void* d_out, int out_size, void* d_ws, size_t ws_size,
                              hipStream_t stream) {
  const void* x    = d_in[0];
  const int*  idxs = (const int*)d_in[1];
  const void* W    = d_in[2];
  const void* bias = d_in[3];

  if (ws_size < WS_NEED) {
    k_fallback<<<T_TOK, 256, 0, stream>>>(x, idxs, W, bias, d_out);
    return;
  }
  char* ws = (char*)d_ws;
  int* flag    = (int*)(ws + FLAG_OFF);
  int* ntiles  = (int*)(ws + NTILES_OFF);
  int4v* table = (int4v*)(ws + TABLE_OFF);
  int* tpad    = (int*)(ws + TPAD_OFF);
  short* Wt    = (short*)(ws + WT_OFF);
  short* xb    = (short*)(ws + XB_OFF);

  k_front<<<1 + TRANS_BLOCKS + CONV_BLOCKS, 1024, 0, stream>>>(
      (const unsigned short*)x, idxs, W, Wt, xb, flag, ntiles, table, tpad);
  k_gemm<<<8 * 8 * TPX, 256, 0, stream>>>(x, xb, bias, Wt, tpad, ntiles, table, flag, d_out);
}